// Round 1
// 94.860 us; speedup vs baseline: 1.0312x; 1.0312x over previous
//
#include <hip/hip_runtime.h>

typedef _Float16 half8 __attribute__((ext_vector_type(8)));
typedef float floatx4 __attribute__((ext_vector_type(4)));
typedef float floatx2 __attribute__((ext_vector_type(2)));
typedef unsigned int uintx2 __attribute__((ext_vector_type(2)));

#define BB 8
#define NN 64
#define DD 64
#define EE 32

__device__ __forceinline__ float sigmoidf_(float x) { return 1.f / (1.f + __expf(-x)); }
__device__ __forceinline__ float tanhf_(float x) {
    float e = __expf(2.f * x);
    return (e - 1.f) / (e + 1.f);
}
__device__ __forceinline__ floatx2 relu2(floatx2 v) {
    floatx2 z = {0.f, 0.f};
    return __builtin_elementwise_max(v, z);
}

// ---------------- prep: W transpose -> fp16 only ----------------
// 64 blocks x 256 threads: WT[d][k] = (fp16)W_e[k][d]   (4096 x 32, A-operand friendly)
__global__ void prep_kernel(const float* __restrict__ W_e, _Float16* __restrict__ WT) {
    const int tid = threadIdx.x;
    const int d   = blockIdx.x * 64 + (tid & 63);
    const int kq  = tid >> 6;                     // k = kq*8 + j
    half8 buf;
#pragma unroll
    for (int j = 0; j < 8; ++j)
        buf[j] = (_Float16)W_e[(kq * 8 + j) * 4096 + d];   // coalesced across d
    *reinterpret_cast<half8*>(WT + d * 32 + kq * 8) = buf;
}

// ---------------- fused: A-GEMM + relu + message + mask + j-sum + GRU1 + GRU2 ----------------
// One block per (b, i_node); 512 threads = 8 waves.
// Main loop: 1 DS op/iter (was 3): quad-fold via permlane32_swap (VALU pipe),
// 32-lane partial write to transposed S[jw][lane][i] (stride 65 -> conflict-free).
// GRU step 1 for this block's own row is computed in-block (threads 256-447),
// overlapped with the P-reduction (threads 0-255). GRU step 2 matmuls split 2x192.
__global__ __launch_bounds__(512, 4)
void fused_kernel(const _Float16* __restrict__ WT,
                  const float* __restrict__ edges,
                  const float* __restrict__ nodes,
                  const float* __restrict__ mask,
                  const float* __restrict__ b_e,
                  const float* __restrict__ K,
                  const float* __restrict__ R,
                  const float* __restrict__ bias,
                  float* __restrict__ out) {
    const int b     = blockIdx.x >> 6;
    const int inode = blockIdx.x & 63;
    const int tid   = threadIdx.x;
    const int w     = tid >> 6;          // 0..7
    const int jw    = w & 3;             // jj-block
    const int ibase = (w >> 2) * 32;     // i-half
    const int lane  = tid & 63;
    const int quad  = lane >> 4;
    const int col   = lane & 15;
    const int row   = b * 64 + inode;

    __shared__ float S[4][32][65];       // [jw][lane<32][i], pad 65 -> conflict-free W&R (33.3 KB)
    __shared__ float P[4][64];
    __shared__ float aggs[64], h1s[64], ns[64];
    __shared__ float gx[192], g1[192], g2[192];

    if (tid < 64) ns[tid] = nodes[row * 64 + tid];   // this block's own x-row (GRU1 input)

    // B-operand fragments from fp32 edges, converted in-register (loop-invariant)
    half8 ef[4];
#pragma unroll
    for (int eb = 0; eb < 4; ++eb) {
        const float* ep = edges + (b * 4096 + inode * 64 + eb * 16 + col) * 32 + quad * 8;
        floatx4 e0 = *reinterpret_cast<const floatx4*>(ep);
        floatx4 e1 = *reinterpret_cast<const floatx4*>(ep + 4);
#pragma unroll
        for (int j = 0; j < 4; ++j) {
            ef[eb][j]     = (_Float16)e0[j];
            ef[eb][4 + j] = (_Float16)e1[j];
        }
    }

    // epilogue multipliers: xm[eb][rp] = {mask*nodes for r=2rp, 2rp+1}
    floatx2 xm[4][2];
#pragma unroll
    for (int eb = 0; eb < 4; ++eb) {
        int j = eb * 16 + col;
        float mk = mask[b * 4096 + inode * 64 + j];
#pragma unroll
        for (int r = 0; r < 4; ++r) {
            int jj = jw * 16 + quad * 4 + r;
            xm[eb][r >> 1][r & 1] = mk * nodes[(b * 64 + j) * 64 + jj];
        }
    }

    // A-operand: WT rows d = i*64 + jw*16 + col, k = quad*8 + j
    const _Float16* aptr = WT + (jw * 16 + col) * 32 + quad * 8;
    const float*    bptr = b_e + jw * 16 + quad * 4;

    // depth-2 software pipeline over this wave's 32 i's
    half8   af0 = *reinterpret_cast<const half8*>(aptr + ibase * 2048);
    floatx4 bf0 = *reinterpret_cast<const floatx4*>(bptr + ibase * 64);
    half8   af1 = *reinterpret_cast<const half8*>(aptr + (ibase + 1) * 2048);
    floatx4 bf1 = *reinterpret_cast<const floatx4*>(bptr + (ibase + 1) * 64);

    for (int ii = 0; ii < 32; ++ii) {
        int ip2 = ibase + ((ii + 2) & 31);   // wrap prefetch (harmless reload at end)
        half8   afn = *reinterpret_cast<const half8*>(aptr + ip2 * 2048);
        floatx4 bfn = *reinterpret_cast<const floatx4*>(bptr + ip2 * 64);

        floatx4 c[4];
        c[0] = __builtin_amdgcn_mfma_f32_16x16x32_f16(af0, ef[0], bf0, 0, 0, 0);
        c[1] = __builtin_amdgcn_mfma_f32_16x16x32_f16(af0, ef[1], bf0, 0, 0, 0);
        c[2] = __builtin_amdgcn_mfma_f32_16x16x32_f16(af0, ef[2], bf0, 0, 0, 0);
        c[3] = __builtin_amdgcn_mfma_f32_16x16x32_f16(af0, ef[3], bf0, 0, 0, 0);

        floatx2 sv = {0.f, 0.f};
#pragma unroll
        for (int eb = 0; eb < 4; ++eb) {
            floatx2* cp = reinterpret_cast<floatx2*>(&c[eb]);
            sv += relu2(cp[0]) * xm[eb][0];
            sv += relu2(cp[1]) * xm[eb][1];
        }
        float s = sv[0] + sv[1];

        // quad-fold 0<->2, 1<->3 on the VALU pipe (not DS): both results summed,
        // so either half-exchange convention of the instruction gives s[l]+s[l^32].
#if __has_builtin(__builtin_amdgcn_permlane32_swap)
        uintx2 pr = __builtin_amdgcn_permlane32_swap(__float_as_uint(s), __float_as_uint(s),
                                                     false, false);
        s = __uint_as_float(pr[0]) + __uint_as_float(pr[1]);
#else
        s += __shfl_xor(s, 32);
#endif
        if (lane < 32) S[jw][lane][ibase + ii] = s;   // 1 DS op/iter, banks (lane+i)%32

        af0 = af1; bf0 = bf1; af1 = afn; bf1 = bfn;
    }
    __syncthreads();

    // phase 1: P-reduction (waves 0-3)  ||  GRU1 x@K part for own row (waves 4-6)
    if (tid < 256) {
        int ii = tid & 63, ww = tid >> 6;
        float p = 0.f;
#pragma unroll
        for (int l = 0; l < 32; ++l) p += S[ww][l][ii];   // stride-1 across lanes: conflict-free
        P[ww][ii] = p;
    } else if (tid < 448) {
        int t = tid - 256;
        float a = bias[t];
#pragma unroll 8
        for (int k = 0; k < 64; ++k) a = fmaf(ns[k], K[k * 192 + t], a);
        gx[t] = a;
    }
    __syncthreads();

    // phase 2: agg row  ||  finish GRU1 (h=0 => h1 = (1-z)*tanh(xh + r*b1h))
    if (tid < 64) {
        aggs[tid] = P[0][tid] + P[1][tid] + P[2][tid] + P[3][tid];
    } else if (tid < 128) {
        int d = tid - 64;
        float z  = sigmoidf_(gx[d]       + bias[192 + d]);
        float r  = sigmoidf_(gx[64 + d]  + bias[256 + d]);
        float hh = tanhf_   (gx[128 + d] + r * bias[320 + d]);
        h1s[d] = (1.f - z) * hh;
    }
    __syncthreads();

    // phase 3: GRU step 2 matmuls, split across 384 threads (two 64-FMA chains in parallel)
    if (tid < 192) {
        float a1 = bias[tid];
#pragma unroll 8
        for (int k = 0; k < 64; ++k) a1 = fmaf(aggs[k], K[k * 192 + tid], a1);
        g1[tid] = a1;
    } else if (tid < 384) {
        int t = tid - 192;
        float a2 = bias[192 + t];
#pragma unroll 8
        for (int k = 0; k < 64; ++k) a2 = fmaf(h1s[k], R[k * 192 + t], a2);
        g2[t] = a2;
    }
    __syncthreads();

    if (tid < 64) {
        float z  = sigmoidf_(g1[tid]       + g2[tid]);
        float r  = sigmoidf_(g1[64 + tid]  + g2[64 + tid]);
        float hh = tanhf_   (g1[128 + tid] + r * g2[128 + tid]);
        out[row * 64 + tid] = z * h1s[tid] + (1.f - z) * hh;
    }
}

extern "C" void kernel_launch(void* const* d_in, const int* in_sizes, int n_in,
                              void* d_out, int out_size, void* d_ws, size_t ws_size,
                              hipStream_t stream) {
    const float* nodes = (const float*)d_in[0];
    const float* edges = (const float*)d_in[1];
    const float* mask  = (const float*)d_in[2];
    const float* W_e   = (const float*)d_in[3];
    const float* b_e   = (const float*)d_in[4];
    const float* gk    = (const float*)d_in[5];
    const float* gr    = (const float*)d_in[6];
    const float* gb    = (const float*)d_in[7];
    float* out = (float*)d_out;

    _Float16* WT = (_Float16*)d_ws;            // 4096*32*2 = 256 KB

    prep_kernel<<<64, 256, 0, stream>>>(W_e, WT);
    fused_kernel<<<512, 512, 0, stream>>>(WT, edges, nodes, mask, b_e, gk, gr, gb, out);
}